// Round 13
// baseline (227.139 us; speedup 1.0000x reference)
//
#include <hip/hip_runtime.h>

#define NN 50000
#define EE 800000
#define D 128
#define PARTSZ 6250  // NN/8

static inline size_t align_up(size_t x, size_t a) { return (x + a - 1) & ~(a - 1); }

__device__ __forceinline__ unsigned pack_bf16(float a, float b) {
    unsigned ua = __float_as_uint(a), ub = __float_as_uint(b);
    unsigned ra = (ua + 0x7fffu + ((ua >> 16) & 1u)) >> 16;
    unsigned rb = (ub + 0x7fffu + ((ub >> 16) & 1u)) & 0xffff0000u;
    return ra | rb;
}
__device__ __forceinline__ float bf_lo(unsigned u) { return __uint_as_float(u << 16); }
__device__ __forceinline__ float bf_hi(unsigned u) { return __uint_as_float(u & 0xffff0000u); }

__global__ void zero_kernel(int* __restrict__ p, int n) {
    int i = blockIdx.x * blockDim.x + threadIdx.x;
    if (i < n) p[i] = 0;
}

// dst-partitioned degree histogram: block b covers chunk b>>3, partition b&7.
__global__ __launch_bounds__(256) void deg_kernel(const int* __restrict__ dst,
                                                  int* __restrict__ deg, int E) {
    int part = blockIdx.x & 7;
    int nch = gridDim.x >> 3;
    int chunk = blockIdx.x >> 3;
    int per = (E + nch - 1) / nch;
    int beg = chunk * per;
    int end = min(E, beg + per);
    int plo = part * PARTSZ, phi = plo + PARTSZ;
    for (int e = beg + threadIdx.x; e < end; e += 256) {
        int d = dst[e];
        if (d >= plo && d < phi) atomicAdd(&deg[d], 1);
    }
}

__global__ void dinv_kernel(const int* __restrict__ deg, float* __restrict__ dinv,
                            float* __restrict__ rdinv, int n) {
    int i = blockIdx.x * blockDim.x + threadIdx.x;
    if (i < n) {
        float d = (float)deg[i];
        if (d < 1.0f) d = 1.0f;
        dinv[i] = rsqrtf(d);
        rdinv[i] = sqrtf(d);
    }
}

// SLICE layout: slice s (of 4) holds channels [32s..32s+32) of all nodes.
// featb[((s*n)+i)*8 + w] = uint2 of 4 bf16 channels (32s + 4w ..+4), pre-scaled by dinv[i].
__global__ void scale_kernel(const float* __restrict__ feat, const float* __restrict__ dinv,
                             uint2* __restrict__ featb, int n) {
    int idx = blockIdx.x * blockDim.x + threadIdx.x;  // over n*32 float4 chunks
    if (idx >= n * 32) return;
    int i = idx >> 5;
    int c = idx & 31;       // channel-chunk of 4: channels 4c..4c+3
    int s = c >> 3;         // slice (0..3)
    int w = c & 7;          // uint2 within slice row
    float di = dinv[i];
    float4 f = ((const float4*)feat)[(size_t)i * 32 + c];
    uint2 p;
    p.x = pack_bf16(f.x * di, f.y * di);
    p.y = pack_bf16(f.z * di, f.w * di);
    featb[((size_t)s * n + i) * 8 + w] = p;
}

__global__ void scan_blk_kernel(const int* __restrict__ deg, int* __restrict__ bscan,
                                int* __restrict__ btot, int n) {
    __shared__ int ws4[4];
    int tid = threadIdx.x, b = blockIdx.x;
    int i = b * 256 + tid;
    int v = (i < n) ? deg[i] : 0;
    int lane = tid & 63, w = tid >> 6;
    int sc = v;
    #pragma unroll
    for (int off = 1; off < 64; off <<= 1) {
        int t = __shfl_up(sc, off);
        if (lane >= off) sc += t;
    }
    if (lane == 63) ws4[w] = sc;
    __syncthreads();
    int woff = 0;
    #pragma unroll
    for (int k = 0; k < 4; ++k)
        if (k < w) woff += ws4[k];
    int inc = sc + woff;
    bscan[b * 256 + tid] = inc;
    if (tid == 255) btot[b] = inc;
}

__global__ void scan_top_kernel(int* __restrict__ btot, int nb) {
    __shared__ int ws4[4];
    int tid = threadIdx.x;
    int v = (tid < nb) ? btot[tid] : 0;
    int lane = tid & 63, w = tid >> 6;
    int sc = v;
    #pragma unroll
    for (int off = 1; off < 64; off <<= 1) {
        int t = __shfl_up(sc, off);
        if (lane >= off) sc += t;
    }
    if (lane == 63) ws4[w] = sc;
    __syncthreads();
    int woff = 0;
    #pragma unroll
    for (int k = 0; k < 4; ++k)
        if (k < w) woff += ws4[k];
    if (tid < nb) btot[tid] = sc + woff - v;
}

__global__ void scan_fix_kernel(const int* __restrict__ bscan, const int* __restrict__ btot,
                                const int* __restrict__ deg, int* __restrict__ rowptr,
                                int* __restrict__ cursor, int n) {
    int i = blockIdx.x * blockDim.x + threadIdx.x;
    if (i >= n) return;
    int inc = bscan[i] + btot[i >> 8];
    rowptr[i + 1] = inc;
    cursor[i] = inc - deg[i];
    if (i == 0) rowptr[0] = 0;
}

// dst-partitioned counting-sort scatter.
__global__ __launch_bounds__(256) void scatter_kernel(const int* __restrict__ src,
                                                      const int* __restrict__ dst,
                                                      int* __restrict__ cursor,
                                                      int* __restrict__ csr_src, int E) {
    int part = blockIdx.x & 7;
    int nch = gridDim.x >> 3;
    int chunk = blockIdx.x >> 3;
    int per = (E + nch - 1) / nch;
    int beg = chunk * per;
    int end = min(E, beg + per);
    int plo = part * PARTSZ, phi = plo + PARTSZ;
    for (int e = beg + threadIdx.x; e < end; e += 256) {
        int d = dst[e];
        if (d >= plo && d < phi) {
            int s = src[e];
            int p = atomicAdd(&cursor[d], 1);
            csr_src[p] = s;
        }
    }
}

#define ACC4(u) do { \
    a0 += bf_lo((u).x); a1 += bf_hi((u).x); \
    a2 += bf_lo((u).y); a3 += bf_hi((u).y); } while (0)

// Slice-resident aggregation, lean form.
// slice = blockIdx&3 (32 channels, 3.2 MB operand slice -> L2-resident per XCD
// under %8 round-robin: XCD x serves slice x%4 only).
// 8 nodes/wave: group g = lane>>3 owns node; lane l3 = lane&7 owns 4 channels
// (uint2). Edge indices read DIRECTLY (identical addr across group -> L1
// broadcast): no shfl, no fold, no predicated adds in the main loop.
// MODE 1: T1b = -di^2 acc   MODE 2: T2b = -2di^2 acc - featb
// MODE 3: t1=T1b*rd, t2=T2b*rd, f=featb*rd, T3=-2di*acc - t1;
//         hb = bf16(th0 f + .5(th1 t1 + th2 t2 + th3 T3) + .5(th1+th2+th3))
template <int MODE>
__global__ __launch_bounds__(256) void agg_kernel(
    const int* __restrict__ rowptr, const int* __restrict__ csr_src,
    const float* __restrict__ dinv, const float* __restrict__ rdinv,
    const uint2* __restrict__ Xb, const uint2* __restrict__ featb,
    const uint2* __restrict__ T1b, const float* __restrict__ theta,
    uint2* __restrict__ outb, int n) {
    int slice = blockIdx.x & 3;
    int lane = threadIdx.x & 63;
    int g = lane >> 3, l3 = lane & 7;
    int node = (blockIdx.x >> 2) * 32 + (threadIdx.x >> 6) * 8 + g;
    bool valid = node < n;
    int nc = valid ? node : 0;
    int beg = rowptr[nc];
    int cnt = valid ? (rowptr[nc + 1] - beg) : 0;
    const uint2* X2 = Xb + (size_t)slice * n * 8;
    float a0 = 0.f, a1 = 0.f, a2 = 0.f, a3 = 0.f;
    int e = 0;
    for (; e + 4 <= cnt; e += 4) {
        int s0 = csr_src[beg + e + 0];
        int s1 = csr_src[beg + e + 1];
        int s2 = csr_src[beg + e + 2];
        int s3 = csr_src[beg + e + 3];
        uint2 u0 = X2[(size_t)s0 * 8 + l3];
        uint2 u1 = X2[(size_t)s1 * 8 + l3];
        uint2 u2 = X2[(size_t)s2 * 8 + l3];
        uint2 u3 = X2[(size_t)s3 * 8 + l3];
        ACC4(u0); ACC4(u1); ACC4(u2); ACC4(u3);
    }
    for (; e < cnt; ++e) {
        int s0 = csr_src[beg + e];
        uint2 u = X2[(size_t)s0 * 8 + l3];
        ACC4(u);
    }
    if (!valid) return;
    float di = dinv[node];
    size_t rr = ((size_t)slice * n + node) * 8 + l3;
    uint2 p;
    if (MODE == 1) {
        float m = -di * di;
        p.x = pack_bf16(m * a0, m * a1);
        p.y = pack_bf16(m * a2, m * a3);
    } else if (MODE == 2) {
        uint2 fb = featb[rr];
        float m = -2.f * di * di;
        p.x = pack_bf16(m * a0 - bf_lo(fb.x), m * a1 - bf_hi(fb.x));
        p.y = pack_bf16(m * a2 - bf_lo(fb.y), m * a3 - bf_hi(fb.y));
    } else {
        uint2 fb = featb[rr];
        uint2 b1 = T1b[rr];
        uint2 b2 = Xb[rr];  // Xb == T2b in mode 3
        float rd = rdinv[node];
        float th0 = theta[0], th1 = theta[1], th2 = theta[2], th3 = theta[3];
        float c = 0.5f * (th1 + th2 + th3);
        float av[4] = {a0, a1, a2, a3};
        float fv[4] = {bf_lo(fb.x), bf_hi(fb.x), bf_lo(fb.y), bf_hi(fb.y)};
        float t1v[4] = {bf_lo(b1.x), bf_hi(b1.x), bf_lo(b1.y), bf_hi(b1.y)};
        float t2v[4] = {bf_lo(b2.x), bf_hi(b2.x), bf_lo(b2.y), bf_hi(b2.y)};
        float h[4];
        #pragma unroll
        for (int k = 0; k < 4; ++k) {
            float t1 = t1v[k] * rd;
            float t2 = t2v[k] * rd;
            float f = fv[k] * rd;
            float t3 = -2.f * di * av[k] - t1;
            h[k] = th0 * f + 0.5f * (th1 * t1 + th2 * t2 + th3 * t3) + c;
        }
        p.x = pack_bf16(h[0], h[1]);
        p.y = pack_bf16(h[2], h[3]);
    }
    outb[rr] = p;
}

// BK-tiled GEMM, bf16 h in 4-slice layout: block computes 64 nodes x 64 outs.
// K-step of 32 channels == exactly one slice.
#define BK 32
#define TS 68
__global__ __launch_bounds__(256) void gemm_kernel(const uint2* __restrict__ hb,
                                                   const float* __restrict__ W,
                                                   float* __restrict__ out, int n) {
    __shared__ float hs[BK * TS];
    __shared__ float ws[BK * TS];
    int tid = threadIdx.x;
    int tile = blockIdx.x >> 1;
    int o0 = (blockIdx.x & 1) * 64;
    int node0 = tile * 64;
    int tx = tid & 15, ty = tid >> 4;

    float acc[4][4] = {};

    for (int k0 = 0; k0 < D; k0 += BK) {
        __syncthreads();
        int s = k0 >> 5;  // slice
        #pragma unroll
        for (int p = 0; p < 2; ++p) {
            int idx = p * 256 + tid;
            int r = idx >> 3, c = idx & 7;  // row r, uint2 c: channels k0+4c..+4
            int nn = node0 + r;
            uint2 u = make_uint2(0u, 0u);
            if (nn < n) u = hb[((size_t)s * n + nn) * 8 + c];
            hs[(c * 4 + 0) * TS + r] = bf_lo(u.x);
            hs[(c * 4 + 1) * TS + r] = bf_hi(u.x);
            hs[(c * 4 + 2) * TS + r] = bf_lo(u.y);
            hs[(c * 4 + 3) * TS + r] = bf_hi(u.y);
            float4 wv = ((const float4*)(W + (size_t)(o0 + r) * D + k0))[c];
            ws[(c * 4 + 0) * TS + r] = wv.x;
            ws[(c * 4 + 1) * TS + r] = wv.y;
            ws[(c * 4 + 2) * TS + r] = wv.z;
            ws[(c * 4 + 3) * TS + r] = wv.w;
        }
        __syncthreads();
        #pragma unroll
        for (int kk = 0; kk < BK; ++kk) {
            float4 hv = *(const float4*)&hs[kk * TS + 4 * ty];
            float4 wv = *(const float4*)&ws[kk * TS + 4 * tx];
            float hvv[4] = {hv.x, hv.y, hv.z, hv.w};
            float wvv[4] = {wv.x, wv.y, wv.z, wv.w};
            #pragma unroll
            for (int k = 0; k < 4; ++k)
                #pragma unroll
                for (int kk2 = 0; kk2 < 4; ++kk2)
                    acc[k][kk2] = fmaf(hvv[k], wvv[kk2], acc[k][kk2]);
        }
    }

    #pragma unroll
    for (int k = 0; k < 4; ++k) {
        int nn = node0 + 4 * ty + k;
        if (nn < n) {
            float4 r4;
            r4.x = acc[k][0] > 0.f ? acc[k][0] : 0.01f * acc[k][0];
            r4.y = acc[k][1] > 0.f ? acc[k][1] : 0.01f * acc[k][1];
            r4.z = acc[k][2] > 0.f ? acc[k][2] : 0.01f * acc[k][2];
            r4.w = acc[k][3] > 0.f ? acc[k][3] : 0.01f * acc[k][3];
            ((float4*)(out + (size_t)nn * D + o0))[tx] = r4;
        }
    }
}

extern "C" void kernel_launch(void* const* d_in, const int* in_sizes, int n_in,
                              void* d_out, int out_size, void* d_ws, size_t ws_size,
                              hipStream_t stream) {
    const float* feat = (const float*)d_in[0];
    const int* src = (const int*)d_in[1];
    const int* dst = (const int*)d_in[2];
    const float* theta = (const float*)d_in[3];
    const float* W = (const float*)d_in[4];
    float* out = (float*)d_out;

    const int n = NN;
    const int E = EE;
    const int nb = (n + 255) / 256;

    char* w = (char*)d_ws;
    size_t off = 0;
    int* deg = (int*)(w + off); off = align_up(off + (size_t)n * 4, 512);
    float* dinv = (float*)(w + off); off = align_up(off + (size_t)n * 4, 512);
    float* rdinv = (float*)(w + off); off = align_up(off + (size_t)n * 4, 512);
    int* rowptr = (int*)(w + off); off = align_up(off + (size_t)(n + 1) * 4, 512);
    int* cursor = (int*)(w + off); off = align_up(off + (size_t)n * 4, 512);
    int* bscan = (int*)(w + off); off = align_up(off + (size_t)(nb * 256) * 4, 512);
    int* btot = (int*)(w + off); off = align_up(off + (size_t)256 * 4, 512);
    int* csr_src = (int*)(w + off); off = align_up(off + (size_t)E * 4, 512);
    uint2* featb = (uint2*)(w + off); off = align_up(off + (size_t)n * 32 * 8, 512);
    uint2* T1b = (uint2*)(w + off); off = align_up(off + (size_t)n * 32 * 8, 512);
    uint2* T2b = (uint2*)(w + off); off = align_up(off + (size_t)n * 32 * 8, 512);
    uint2* hb = (uint2*)(w + off); off = align_up(off + (size_t)n * 32 * 8, 512);
    (void)ws_size;

    zero_kernel<<<(n + 255) / 256, 256, 0, stream>>>(deg, n);
    deg_kernel<<<2048, 256, 0, stream>>>(dst, deg, E);
    dinv_kernel<<<(n + 255) / 256, 256, 0, stream>>>(deg, dinv, rdinv, n);
    scale_kernel<<<(n * 32 + 255) / 256, 256, 0, stream>>>(feat, dinv, featb, n);
    scan_blk_kernel<<<nb, 256, 0, stream>>>(deg, bscan, btot, n);
    scan_top_kernel<<<1, 256, 0, stream>>>(btot, nb);
    scan_fix_kernel<<<(n + 255) / 256, 256, 0, stream>>>(bscan, btot, deg, rowptr, cursor, n);
    scatter_kernel<<<2048, 256, 0, stream>>>(src, dst, cursor, csr_src, E);

    int agg_grid = ((n + 31) / 32) * 4;  // node-chunks (32/block) x 4 slices
    agg_kernel<1><<<agg_grid, 256, 0, stream>>>(rowptr, csr_src, dinv, rdinv, featb, featb, T1b, theta, T1b, n);
    agg_kernel<2><<<agg_grid, 256, 0, stream>>>(rowptr, csr_src, dinv, rdinv, T1b, featb, T1b, theta, T2b, n);
    agg_kernel<3><<<agg_grid, 256, 0, stream>>>(rowptr, csr_src, dinv, rdinv, T2b, featb, T1b, theta, hb, n);

    int gemm_grid = ((n + 63) / 64) * 2;
    gemm_kernel<<<gemm_grid, 256, 0, stream>>>(hb, W, out, n);
}

// Round 15
// 215.383 us; speedup vs baseline: 1.0546x; 1.0546x over previous
//
#include <hip/hip_runtime.h>

#define NN 50000
#define EE 800000
#define D 128
#define PARTSZ 6250  // NN/8

static inline size_t align_up(size_t x, size_t a) { return (x + a - 1) & ~(a - 1); }

__device__ __forceinline__ unsigned pack_bf16(float a, float b) {
    unsigned ua = __float_as_uint(a), ub = __float_as_uint(b);
    unsigned ra = (ua + 0x7fffu + ((ua >> 16) & 1u)) >> 16;
    unsigned rb = (ub + 0x7fffu + ((ub >> 16) & 1u)) & 0xffff0000u;
    return ra | rb;
}
__device__ __forceinline__ float bf_lo(unsigned u) { return __uint_as_float(u << 16); }
__device__ __forceinline__ float bf_hi(unsigned u) { return __uint_as_float(u & 0xffff0000u); }

__global__ void zero_kernel(int* __restrict__ p, int n) {
    int i = blockIdx.x * blockDim.x + threadIdx.x;
    if (i < n) p[i] = 0;
}

// dst-partitioned degree histogram: block b covers chunk b>>3, partition b&7.
__global__ __launch_bounds__(256) void deg_kernel(const int* __restrict__ dst,
                                                  int* __restrict__ deg, int E) {
    int part = blockIdx.x & 7;
    int nch = gridDim.x >> 3;
    int chunk = blockIdx.x >> 3;
    int per = (E + nch - 1) / nch;
    int beg = chunk * per;
    int end = min(E, beg + per);
    int plo = part * PARTSZ, phi = plo + PARTSZ;
    for (int e = beg + threadIdx.x; e < end; e += 256) {
        int d = dst[e];
        if (d >= plo && d < phi) atomicAdd(&deg[d], 1);
    }
}

__global__ void dinv_kernel(const int* __restrict__ deg, float* __restrict__ dinv,
                            float* __restrict__ rdinv, int n) {
    int i = blockIdx.x * blockDim.x + threadIdx.x;
    if (i < n) {
        float d = (float)deg[i];
        if (d < 1.0f) d = 1.0f;
        dinv[i] = rsqrtf(d);
        rdinv[i] = sqrtf(d);
    }
}

// Row-major packed layout: featb[i*64 + c2] = bf16x2 of channels (2c2, 2c2+1), pre-scaled.
__global__ void scale_kernel(const float* __restrict__ feat, const float* __restrict__ dinv,
                             unsigned* __restrict__ featb, int n) {
    int idx = blockIdx.x * blockDim.x + threadIdx.x;
    if (idx >= n * 64) return;
    int i = idx >> 6;
    float di = dinv[i];
    float2 f = ((const float2*)feat)[idx];
    featb[idx] = pack_bf16(f.x * di, f.y * di);
}

__global__ void scan_blk_kernel(const int* __restrict__ deg, int* __restrict__ bscan,
                                int* __restrict__ btot, int n) {
    __shared__ int ws4[4];
    int tid = threadIdx.x, b = blockIdx.x;
    int i = b * 256 + tid;
    int v = (i < n) ? deg[i] : 0;
    int lane = tid & 63, w = tid >> 6;
    int sc = v;
    #pragma unroll
    for (int off = 1; off < 64; off <<= 1) {
        int t = __shfl_up(sc, off);
        if (lane >= off) sc += t;
    }
    if (lane == 63) ws4[w] = sc;
    __syncthreads();
    int woff = 0;
    #pragma unroll
    for (int k = 0; k < 4; ++k)
        if (k < w) woff += ws4[k];
    int inc = sc + woff;
    bscan[b * 256 + tid] = inc;
    if (tid == 255) btot[b] = inc;
}

__global__ void scan_top_kernel(int* __restrict__ btot, int nb) {
    __shared__ int ws4[4];
    int tid = threadIdx.x;
    int v = (tid < nb) ? btot[tid] : 0;
    int lane = tid & 63, w = tid >> 6;
    int sc = v;
    #pragma unroll
    for (int off = 1; off < 64; off <<= 1) {
        int t = __shfl_up(sc, off);
        if (lane >= off) sc += t;
    }
    if (lane == 63) ws4[w] = sc;
    __syncthreads();
    int woff = 0;
    #pragma unroll
    for (int k = 0; k < 4; ++k)
        if (k < w) woff += ws4[k];
    if (tid < nb) btot[tid] = sc + woff - v;
}

__global__ void scan_fix_kernel(const int* __restrict__ bscan, const int* __restrict__ btot,
                                const int* __restrict__ deg, int* __restrict__ rowptr,
                                int* __restrict__ cursor, int n) {
    int i = blockIdx.x * blockDim.x + threadIdx.x;
    if (i >= n) return;
    int inc = bscan[i] + btot[i >> 8];
    rowptr[i + 1] = inc;
    cursor[i] = inc - deg[i];
    if (i == 0) rowptr[0] = 0;
}

// dst-partitioned counting-sort scatter.
__global__ __launch_bounds__(256) void scatter_kernel(const int* __restrict__ src,
                                                      const int* __restrict__ dst,
                                                      int* __restrict__ cursor,
                                                      int* __restrict__ csr_src, int E) {
    int part = blockIdx.x & 7;
    int nch = gridDim.x >> 3;
    int chunk = blockIdx.x >> 3;
    int per = (E + nch - 1) / nch;
    int beg = chunk * per;
    int end = min(E, beg + per);
    int plo = part * PARTSZ, phi = plo + PARTSZ;
    for (int e = beg + threadIdx.x; e < end; e += 256) {
        int d = dst[e];
        if (d >= plo && d < phi) {
            int s = src[e];
            int p = atomicAdd(&cursor[d], 1);
            csr_src[p] = s;
        }
    }
}

#define ACC8(u) do { \
    a0 += bf_lo((u).x); a1 += bf_hi((u).x); \
    a2 += bf_lo((u).y); a3 += bf_hi((u).y); \
    a4 += bf_lo((u).z); a5 += bf_hi((u).z); \
    a6 += bf_lo((u).w); a7 += bf_hi((u).w); } while (0)

// 4 nodes per wave: quarter q = lane>>4 owns node; lane hq = lane&15 owns
// channels [8hq..8hq+7] (uint4 loads). Software-pipelined: next batch's
// csr_src indices are loaded BEFORE the current batch's 16 gathers issue;
// no ballot-branches inside the batch (OOB slots gather row 0, L1-hot,
// adds predicated off). No cross-lane fold.
// MODE 1: T1b = -di^2 acc   MODE 2: T2b = -2di^2 acc - featb
// MODE 3: t1=T1b*rd, t2=T2b*rd, f=featb*rd, T3=-2di*acc - t1;
//         hb = bf16(th0 f + .5(th1 t1 + th2 t2 + th3 T3) + .5(th1+th2+th3))
template <int MODE>
__global__ __launch_bounds__(256) void agg_kernel(
    const int* __restrict__ rowptr, const int* __restrict__ csr_src,
    const float* __restrict__ dinv, const float* __restrict__ rdinv,
    const unsigned* __restrict__ Xb, const unsigned* __restrict__ featb,
    const unsigned* __restrict__ T1b, const float* __restrict__ theta,
    unsigned* __restrict__ outb, int n) {
    int lane = threadIdx.x & 63;
    int q = lane >> 4;
    int hq = lane & 15;
    int node = (blockIdx.x * 4 + (threadIdx.x >> 6)) * 4 + q;
    bool valid = node < n;
    int nclamp = valid ? node : 0;
    int beg = rowptr[nclamp];
    int cnt = valid ? (rowptr[nclamp + 1] - beg) : 0;
    const uint4* X4 = (const uint4*)Xb;
    float a0 = 0.f, a1 = 0.f, a2 = 0.f, a3 = 0.f, a4 = 0.f, a5 = 0.f, a6 = 0.f, a7 = 0.f;
    int qb = q << 4;
    int s = (hq < cnt) ? csr_src[beg + hq] : 0;
    for (int base = 0; __any(base < cnt); base += 16) {
        int rem = cnt - base;
        int snext = (hq < rem - 16) ? csr_src[beg + base + 16 + hq] : 0;
        #pragma unroll
        for (int j = 0; j < 16; j += 4) {
            int s0 = __shfl(s, qb + j + 0);
            int s1 = __shfl(s, qb + j + 1);
            int s2 = __shfl(s, qb + j + 2);
            int s3 = __shfl(s, qb + j + 3);
            uint4 u0 = X4[(size_t)s0 * 16 + hq];
            uint4 u1 = X4[(size_t)s1 * 16 + hq];
            uint4 u2 = X4[(size_t)s2 * 16 + hq];
            uint4 u3 = X4[(size_t)s3 * 16 + hq];
            if (j + 0 < rem) ACC8(u0);
            if (j + 1 < rem) ACC8(u1);
            if (j + 2 < rem) ACC8(u2);
            if (j + 3 < rem) ACC8(u3);
        }
        s = snext;
    }
    if (!valid) return;
    float di = dinv[node];
    size_t r16 = (size_t)node * 16 + hq;
    uint4 p;
    if (MODE == 1) {
        float m = -di * di;
        p.x = pack_bf16(m * a0, m * a1);
        p.y = pack_bf16(m * a2, m * a3);
        p.z = pack_bf16(m * a4, m * a5);
        p.w = pack_bf16(m * a6, m * a7);
    } else if (MODE == 2) {
        uint4 fb = ((const uint4*)featb)[r16];
        float m = -2.f * di * di;
        p.x = pack_bf16(m * a0 - bf_lo(fb.x), m * a1 - bf_hi(fb.x));
        p.y = pack_bf16(m * a2 - bf_lo(fb.y), m * a3 - bf_hi(fb.y));
        p.z = pack_bf16(m * a4 - bf_lo(fb.z), m * a5 - bf_hi(fb.z));
        p.w = pack_bf16(m * a6 - bf_lo(fb.w), m * a7 - bf_hi(fb.w));
    } else {
        uint4 fb = ((const uint4*)featb)[r16];
        uint4 b1 = ((const uint4*)T1b)[r16];
        uint4 b2 = ((const uint4*)Xb)[r16];  // Xb == T2b in mode 3
        float rd = rdinv[node];
        float th0 = theta[0], th1 = theta[1], th2 = theta[2], th3 = theta[3];
        float c = 0.5f * (th1 + th2 + th3);
        float av[8] = {a0, a1, a2, a3, a4, a5, a6, a7};
        float fv[8] = {bf_lo(fb.x), bf_hi(fb.x), bf_lo(fb.y), bf_hi(fb.y),
                       bf_lo(fb.z), bf_hi(fb.z), bf_lo(fb.w), bf_hi(fb.w)};
        float t1v[8] = {bf_lo(b1.x), bf_hi(b1.x), bf_lo(b1.y), bf_hi(b1.y),
                        bf_lo(b1.z), bf_hi(b1.z), bf_lo(b1.w), bf_hi(b1.w)};
        float t2v[8] = {bf_lo(b2.x), bf_hi(b2.x), bf_lo(b2.y), bf_hi(b2.y),
                        bf_lo(b2.z), bf_hi(b2.z), bf_lo(b2.w), bf_hi(b2.w)};
        float h[8];
        #pragma unroll
        for (int k = 0; k < 8; ++k) {
            float t1 = t1v[k] * rd;
            float t2 = t2v[k] * rd;
            float f = fv[k] * rd;
            float t3 = -2.f * di * av[k] - t1;
            h[k] = th0 * f + 0.5f * (th1 * t1 + th2 * t2 + th3 * t3) + c;
        }
        p.x = pack_bf16(h[0], h[1]);
        p.y = pack_bf16(h[2], h[3]);
        p.z = pack_bf16(h[4], h[5]);
        p.w = pack_bf16(h[6], h[7]);
    }
    ((uint4*)outb)[r16] = p;
}

// BK-tiled GEMM, bf16 h input: block computes 64 nodes x 64 outs, K in 4 steps of 32.
#define BK 32
#define TS 68
__global__ __launch_bounds__(256) void gemm_kernel(const unsigned* __restrict__ hb,
                                                   const float* __restrict__ W,
                                                   float* __restrict__ out, int n) {
    __shared__ float hs[BK * TS];
    __shared__ float ws[BK * TS];
    int tid = threadIdx.x;
    int tile = blockIdx.x >> 1;
    int o0 = (blockIdx.x & 1) * 64;
    int node0 = tile * 64;
    int tx = tid & 15, ty = tid >> 4;
    const uint2* H2 = (const uint2*)hb;

    float acc[4][4] = {};

    for (int k0 = 0; k0 < D; k0 += BK) {
        __syncthreads();
        #pragma unroll
        for (int p = 0; p < 2; ++p) {
            int idx = p * 256 + tid;
            int r = idx >> 3, c = idx & 7;
            int nn = node0 + r;
            uint2 u = make_uint2(0u, 0u);
            if (nn < n) u = H2[(size_t)nn * 32 + (k0 >> 2) + c];
            hs[(c * 4 + 0) * TS + r] = bf_lo(u.x);
            hs[(c * 4 + 1) * TS + r] = bf_hi(u.x);
            hs[(c * 4 + 2) * TS + r] = bf_lo(u.y);
            hs[(c * 4 + 3) * TS + r] = bf_hi(u.y);
            float4 wv = ((const float4*)(W + (size_t)(o0 + r) * D + k0))[c];
            ws[(c * 4 + 0) * TS + r] = wv.x;
            ws[(c * 4 + 1) * TS + r] = wv.y;
            ws[(c * 4 + 2) * TS + r] = wv.z;
            ws[(c * 4 + 3) * TS + r] = wv.w;
        }
        __syncthreads();
        #pragma unroll
        for (int kk = 0; kk < BK; ++kk) {
            float4 hv = *(const float4*)&hs[kk * TS + 4 * ty];
            float4 wv = *(const float4*)&ws[kk * TS + 4 * tx];
            float hvv[4] = {hv.x, hv.y, hv.z, hv.w};
            float wvv[4] = {wv.x, wv.y, wv.z, wv.w};
            #pragma unroll
            for (int k = 0; k < 4; ++k)
                #pragma unroll
                for (int kk2 = 0; kk2 < 4; ++kk2)
                    acc[k][kk2] = fmaf(hvv[k], wvv[kk2], acc[k][kk2]);
        }
    }

    #pragma unroll
    for (int k = 0; k < 4; ++k) {
        int nn = node0 + 4 * ty + k;
        if (nn < n) {
            float4 r4;
            r4.x = acc[k][0] > 0.f ? acc[k][0] : 0.01f * acc[k][0];
            r4.y = acc[k][1] > 0.f ? acc[k][1] : 0.01f * acc[k][1];
            r4.z = acc[k][2] > 0.f ? acc[k][2] : 0.01f * acc[k][2];
            r4.w = acc[k][3] > 0.f ? acc[k][3] : 0.01f * acc[k][3];
            ((float4*)(out + (size_t)nn * D + o0))[tx] = r4;
        }
    }
}

extern "C" void kernel_launch(void* const* d_in, const int* in_sizes, int n_in,
                              void* d_out, int out_size, void* d_ws, size_t ws_size,
                              hipStream_t stream) {
    const float* feat = (const float*)d_in[0];
    const int* src = (const int*)d_in[1];
    const int* dst = (const int*)d_in[2];
    const float* theta = (const float*)d_in[3];
    const float* W = (const float*)d_in[4];
    float* out = (float*)d_out;

    const int n = NN;
    const int E = EE;
    const int nb = (n + 255) / 256;

    char* w = (char*)d_ws;
    size_t off = 0;
    int* deg = (int*)(w + off); off = align_up(off + (size_t)n * 4, 512);
    float* dinv = (float*)(w + off); off = align_up(off + (size_t)n * 4, 512);
    float* rdinv = (float*)(w + off); off = align_up(off + (size_t)n * 4, 512);
    int* rowptr = (int*)(w + off); off = align_up(off + (size_t)(n + 1) * 4, 512);
    int* cursor = (int*)(w + off); off = align_up(off + (size_t)n * 4, 512);
    int* bscan = (int*)(w + off); off = align_up(off + (size_t)(nb * 256) * 4, 512);
    int* btot = (int*)(w + off); off = align_up(off + (size_t)256 * 4, 512);
    int* csr_src = (int*)(w + off); off = align_up(off + (size_t)E * 4, 512);
    unsigned* featb = (unsigned*)(w + off); off = align_up(off + (size_t)n * 64 * 4, 512);
    unsigned* T1b = (unsigned*)(w + off); off = align_up(off + (size_t)n * 64 * 4, 512);
    unsigned* T2b = (unsigned*)(w + off); off = align_up(off + (size_t)n * 64 * 4, 512);
    unsigned* hb = (unsigned*)(w + off); off = align_up(off + (size_t)n * 64 * 4, 512);
    (void)ws_size;

    zero_kernel<<<(n + 255) / 256, 256, 0, stream>>>(deg, n);
    deg_kernel<<<2048, 256, 0, stream>>>(dst, deg, E);
    dinv_kernel<<<(n + 255) / 256, 256, 0, stream>>>(deg, dinv, rdinv, n);
    scale_kernel<<<(n * 64 + 255) / 256, 256, 0, stream>>>(feat, dinv, featb, n);
    scan_blk_kernel<<<nb, 256, 0, stream>>>(deg, bscan, btot, n);
    scan_top_kernel<<<1, 256, 0, stream>>>(btot, nb);
    scan_fix_kernel<<<(n + 255) / 256, 256, 0, stream>>>(bscan, btot, deg, rowptr, cursor, n);
    scatter_kernel<<<2048, 256, 0, stream>>>(src, dst, cursor, csr_src, E);

    int agg_grid = (n + 15) / 16;  // 4 waves/block x 4 nodes/wave
    agg_kernel<1><<<agg_grid, 256, 0, stream>>>(rowptr, csr_src, dinv, rdinv, featb, featb, T1b, theta, T1b, n);
    agg_kernel<2><<<agg_grid, 256, 0, stream>>>(rowptr, csr_src, dinv, rdinv, T1b, featb, T1b, theta, T2b, n);
    agg_kernel<3><<<agg_grid, 256, 0, stream>>>(rowptr, csr_src, dinv, rdinv, T2b, featb, T1b, theta, hb, n);

    int gemm_grid = ((n + 63) / 64) * 2;
    gemm_kernel<<<gemm_grid, 256, 0, stream>>>(hb, W, out, n);
}